// Round 5
// baseline (2136.328 us; speedup 1.0000x reference)
//
#include <hip/hip_runtime.h>
#include <hip/hip_bf16.h>

// ---------------------------------------------------------------------------
// AJ-RNN forward: 2-layer LSTM (B=128,T=256,D=64,H=512) with missing-value
// imputation. Round 8: persistent kernel, TAG-IN-DATA rendezvous.
//  - R7 post-mortem: split-K added sync+reduce overhead (1675us vs R6 1515).
//    Reverted to R6 gate-split (wave w = gate w; 1 zb write + 4 reads).
//  - h exchanged as tagged u32 = (t<<16)|bf16 at the LLC coherence point
//    (sc0 sc1). Data IS the flag: consumer polls its own 128B slice until all
//    tags==t, values then already in registers -> strip tags -> LDS. Kills
//    the serialized {vmcnt drain, flag store, flag poll, data load} chain
//    (~2 LLC RTTs/step). Single buffer per h is safe: dependence chain bounds
//    producer/consumer skew to < 1 overwrite distance.
//  - z1's h1-part hoisted to top of step (overlaps producers' h2 stores);
//    z2's h2-half computed by all 4 waves inside the h1 rendezvous window.
// ---------------------------------------------------------------------------

typedef __bf16        v8bf  __attribute__((ext_vector_type(8)));
typedef float         f32x4 __attribute__((ext_vector_type(4)));
typedef unsigned int  u32x4 __attribute__((ext_vector_type(4)));

constexpr int B_ = 128, T_ = 256, D_ = 64, H_ = 512;

// workspace layout (bytes)
constexpr size_t OFF_WP1 = 0;        // packed [k0;r0] bf16 -> 2359296 B
constexpr size_t OFF_WP2 = 2359296;  // packed [k1;r1] bf16 -> 4194304 B
constexpr size_t OFF_WPP = 6553600;  // packed W bf16       ->   65536 B
constexpr size_t OFF_H1T = 6619136;  // h1 tagged u32 [128][512] -> 262144 B
constexpr size_t OFF_H2T = 6881280;  // h2 tagged u32 [128][512] -> 262144 B
// total 7143424 B

__device__ __forceinline__ v8bf ldv(const __hip_bfloat16* p) {
  return *reinterpret_cast<const v8bf*>(p);
}
__device__ __forceinline__ f32x4 MF(v8bf a, v8bf b, f32x4 c) {
  return __builtin_amdgcn_mfma_f32_16x16x32_bf16(a, b, c, 0, 0, 0);
}
__device__ __forceinline__ float sigf(float x) { return 1.0f / (1.0f + __expf(-x)); }
__device__ __forceinline__ float tanhfast(float x) {
  x = fminf(15.0f, fmaxf(-15.0f, x));
  float e = __expf(-2.0f * x);
  return (1.0f - e) / (1.0f + e);
}

// 32-bit store straight to the device coherence point (LLC).
__device__ __forceinline__ void st_llc_u32(void* p, unsigned v) {
  asm volatile("global_store_dword %0, %1, off sc0 sc1" :: "v"(p), "v"(v) : "memory");
}

// Poll own 128B tagged slice (32 u32) at the LLC until every tag == tag,
// then strip tags and land 64B of bf16 into swizzled LDS.
__device__ __forceinline__ void poll_land(const unsigned* g, unsigned tag,
                                          char* lrow, int so0, int ssw) {
  u32x4 v0, v1, v2, v3, v4, v5, v6, v7;
  for (;;) {
    asm volatile(
        "global_load_dwordx4 %0, %8, off sc0 sc1\n\t"
        "global_load_dwordx4 %1, %8, off offset:16 sc0 sc1\n\t"
        "global_load_dwordx4 %2, %8, off offset:32 sc0 sc1\n\t"
        "global_load_dwordx4 %3, %8, off offset:48 sc0 sc1\n\t"
        "global_load_dwordx4 %4, %8, off offset:64 sc0 sc1\n\t"
        "global_load_dwordx4 %5, %8, off offset:80 sc0 sc1\n\t"
        "global_load_dwordx4 %6, %8, off offset:96 sc0 sc1\n\t"
        "global_load_dwordx4 %7, %8, off offset:112 sc0 sc1\n\t"
        "s_waitcnt vmcnt(0)"
        : "=&v"(v0), "=&v"(v1), "=&v"(v2), "=&v"(v3),
          "=&v"(v4), "=&v"(v5), "=&v"(v6), "=&v"(v7)
        : "v"(g) : "memory");
    unsigned bad = 0;
#define CKT(v) bad |= ((v[0] >> 16) ^ tag) | ((v[1] >> 16) ^ tag) | \
                      ((v[2] >> 16) ^ tag) | ((v[3] >> 16) ^ tag)
    CKT(v0); CKT(v1); CKT(v2); CKT(v3); CKT(v4); CKT(v5); CKT(v6); CKT(v7);
#undef CKT
    if (bad == 0) break;
    __builtin_amdgcn_s_sleep(1);
  }
#define PK(lo, hi) (((lo) & 0xffffu) | ((hi) << 16))
  u32x4 p;
  p[0]=PK(v0[0],v0[1]); p[1]=PK(v0[2],v0[3]); p[2]=PK(v1[0],v1[1]); p[3]=PK(v1[2],v1[3]);
  *(u32x4*)(lrow + ((so0 +  0) ^ ssw)) = p;
  p[0]=PK(v2[0],v2[1]); p[1]=PK(v2[2],v2[3]); p[2]=PK(v3[0],v3[1]); p[3]=PK(v3[2],v3[3]);
  *(u32x4*)(lrow + ((so0 + 16) ^ ssw)) = p;
  p[0]=PK(v4[0],v4[1]); p[1]=PK(v4[2],v4[3]); p[2]=PK(v5[0],v5[1]); p[3]=PK(v5[2],v5[3]);
  *(u32x4*)(lrow + ((so0 + 32) ^ ssw)) = p;
  p[0]=PK(v6[0],v6[1]); p[1]=PK(v6[2],v6[3]); p[2]=PK(v7[0],v7[1]); p[3]=PK(v7[2],v7[3]);
  *(u32x4*)(lrow + ((so0 + 48) ^ ssw)) = p;
#undef PK
}

// ---------------------------------------------------------------------------
// Pack B-operand fragments (float32 in, bf16 out):
// out[((ct*nkc + kc)*64 + lane)*8 + j] = Wcat[kc*32 + (lane>>4)*8 + j][ct*16 + (lane&15)]
// ---------------------------------------------------------------------------
__global__ __launch_bounds__(256) void pack_weights(
    const float* __restrict__ kp, const float* __restrict__ rp,
    int krows, int ncols, int nkc, int nct, __hip_bfloat16* __restrict__ out) {
  int tid = blockIdx.x * 256 + threadIdx.x;
  int total = nct * nkc * 64;
  if (tid >= total) return;
  int L  = tid & 63;
  int kc = (tid >> 6) % nkc;
  int ct = tid / (64 * nkc);
  int n  = ct * 16 + (L & 15);
  int kb = kc * 32 + (L >> 4) * 8;
  __hip_bfloat16* dst = out + (size_t)tid * 8;
#pragma unroll
  for (int j = 0; j < 8; ++j) {
    int kk = kb + j;
    float v = (kk < krows) ? kp[kk * ncols + n] : rp[(kk - krows) * ncols + n];
    dst[j] = __float2bfloat16(v);
  }
}

// init tagged buffers to tag 0xFFFF (never a valid t); ws re-poisoned per call
__global__ __launch_bounds__(256) void init_state(
    unsigned* __restrict__ h1t, unsigned* __restrict__ h2t) {
  int idx = blockIdx.x * 256 + threadIdx.x;   // 65536 total
  h1t[idx] = 0xFFFF0000u;
  h2t[idx] = 0xFFFF0000u;
}

// ---------------------------------------------------------------------------
// Persistent recurrence kernel. Block = (rg,cg): 16 batch rows x 16 h-cols,
// 4 waves (gate-split: wave w = gate w). 8 chains of 32 blocks; rg=blockIdx&7
// so a chain's blocks round-robin to the same XCD (perf heuristic only).
// ---------------------------------------------------------------------------
__global__ __launch_bounds__(256, 1) void rnn_persist(
    const float* __restrict__ x,
    const __hip_bfloat16* __restrict__ Wp1,
    const __hip_bfloat16* __restrict__ Wp2,
    const __hip_bfloat16* __restrict__ WpP,
    const float* __restrict__ b0,
    const float* __restrict__ b1,
    const float* __restrict__ biasD,
    unsigned* __restrict__ h1t,
    unsigned* __restrict__ h2t,
    float* __restrict__ pred_out,
    float* __restrict__ last_out) {

  // h tiles: 1024B rows, XOR-swizzled (phys_byte = log_byte ^ ((row&7)<<4))
  __shared__ alignas(16) __hip_bfloat16 h1P[16][512];
  __shared__ alignas(16) __hip_bfloat16 h1Q[16][512];
  __shared__ alignas(16) __hip_bfloat16 h2L[16][512];
  __shared__ alignas(16) __hip_bfloat16 curL[16][72];
  __shared__ alignas(16) float predb[16][68];
  __shared__ float zb[4][16][17];

  const int tid = threadIdx.x;
  const int rg = blockIdx.x & 7;
  const int cg = blockIdx.x >> 3;
  const int w  = tid >> 6;
  const int L  = tid & 63;
  const int m  = L & 15;
  const int q  = L >> 4;
  const int row2 = tid >> 4;
  const int col2 = tid & 15;
  const int C  = cg * 16 + col2;
  const int R  = rg * 16 + row2;
  const int c0 = col2 * 4;
  const int sw = (m & 7) << 3;          // element-unit LDS read swizzle

  // poll-slice addressing: thread owns row (tid>>4), cols (tid&15)*32..+31
  const unsigned* h2slice = h2t + (size_t)rg * 8192 + tid * 32;
  const unsigned* h1slice = h1t + (size_t)rg * 8192 + tid * 32;
  const int so0 = (tid & 15) * 64;      // byte offset of slice within LDS row
  const int ssw = (row2 & 7) << 4;      // byte swizzle for landing row
  char* h2row = (char*)&h2L[row2][0];
  const unsigned gsidx = (unsigned)rg * 8192 + row2 * 512 + cg * 16 + col2;

  // ---- weight fragments into registers, once (gate-split layout) ----
  v8bf wpp[16], wp1[18], wp2[32];
  {
    const int ct = w * 32 + cg;
#pragma unroll
    for (int kc = 0; kc < 16; ++kc)
      wpp[kc] = ldv(WpP + ((size_t)(w * 16 + kc) * 64 + L) * 8);
#pragma unroll
    for (int kc = 0; kc < 18; ++kc)
      wp1[kc] = ldv(Wp1 + ((size_t)(ct * 18 + kc) * 64 + L) * 8);
#pragma unroll
    for (int kc = 0; kc < 32; ++kc)
      wp2[kc] = ldv(Wp2 + ((size_t)(ct * 32 + kc) * 64 + L) * 8);
  }
  const float b0i = b0[C], b0f = b0[512 + C], b0g = b0[1024 + C], b0o = b0[1536 + C];
  const float b1i = b1[C], b1f = b1[512 + C], b1g = b1[1024 + C], b1o = b1[1536 + C];
  const float bD  = biasD[w * 16 + m];

  float c1v = 0.0f, c2v = 0.0f;         // cell state in registers

  const float* xrow = x + (size_t)R * T_ * D_;
  float* prow = pred_out + (size_t)R * (T_ - 1) * D_;
  const int hidx = R * H_ + C;

  // prologue: h1(-1)=0 (ping) and h2(-1)=0 directly in LDS
  {
    u32x4 zz = {0u, 0u, 0u, 0u};
    u32x4* p1 = reinterpret_cast<u32x4*>(&h1P[0][0]);
    u32x4* p2 = reinterpret_cast<u32x4*>(&h2L[0][0]);
#pragma unroll
    for (int i = 0; i < 4; ++i) { p1[tid * 4 + i] = zz; p2[tid * 4 + i] = zz; }
  }
  __syncthreads();

  for (int t = 0; t < T_; ++t) {
    __hip_bfloat16 (*h1L)[512] = (t & 1) ? h1Q : h1P;  // h1_{t-1} (LDS-resident)
    __hip_bfloat16 (*h1N)[512] = (t & 1) ? h1P : h1Q;  // h1_t (landed below)

    const float4 xv = *reinterpret_cast<const float4*>(xrow + t * D_ + c0);

    // ---- P0: z1 h1-part (gate w, 16 chunks) - no new data needed;
    //          overlaps other blocks still storing h2_{t-1} ----
    f32x4 z1a = {0.f,0.f,0.f,0.f}, z1b = {0.f,0.f,0.f,0.f};
#pragma unroll
    for (int c = 0; c < 16; c += 2) {
      v8bf a0 = ldv(&h1L[m][(c * 32 + q * 8) ^ sw]);
      v8bf a1 = ldv(&h1L[m][((c + 1) * 32 + q * 8) ^ sw]);
      z1a = MF(a0, wp1[2 + c], z1a);
      z1b = MF(a1, wp1[3 + c], z1b);
    }

    // ---- P1: tagged poll+land h2_{t-1} (each thread its own 128B slice) ----
    if (t > 0) poll_land(h2slice, (unsigned)(t - 1), h2row, so0, ssw);
    __syncthreads();

    // ---- P2: pred = h2_{t-1} @ W + bias (wave w: cols w*16..+15) ----
    if (t > 0) {
      f32x4 a0 = {0.f,0.f,0.f,0.f}, a1 = {0.f,0.f,0.f,0.f};
#pragma unroll
      for (int kc = 0; kc < 16; kc += 2) {
        v8bf x0 = ldv(&h2L[m][(kc * 32 + q * 8) ^ sw]);
        v8bf x1 = ldv(&h2L[m][((kc + 1) * 32 + q * 8) ^ sw]);
        a0 = MF(x0, wpp[kc], a0);
        a1 = MF(x1, wpp[kc + 1], a1);
      }
      a0 += a1;
#pragma unroll
      for (int r = 0; r < 4; ++r) predb[q * 4 + r][w * 16 + m] = a0[r] + bD;
    }
    __syncthreads();

    // ---- P3: cur build; cg==0 streams pred -> d_out ----
    {
      float4 pv = {0.f, 0.f, 0.f, 0.f};
      if (t > 0) pv = *reinterpret_cast<const float4*>(&predb[row2][c0]);
      const float xa[4] = {xv.x, xv.y, xv.z, xv.w};
      const float pa[4] = {pv.x, pv.y, pv.z, pv.w};
#pragma unroll
      for (int j = 0; j < 4; ++j) {
        const bool missv = (t > 0) && (xa[j] == 128.0f);
        curL[row2][c0 + j] = __float2bfloat16(missv ? pa[j] : xa[j]);
      }
      if (cg == 0 && t > 0)
        *reinterpret_cast<float4*>(prow + (size_t)(t - 1) * D_ + c0) = pv;
    }
    __syncthreads();

    // ---- P4: z1 cur-part + z1 gate tile -> zb ----
    {
      v8bf a0 = ldv(&curL[m][q * 8]);
      v8bf a1 = ldv(&curL[m][32 + q * 8]);
      z1a = MF(a0, wp1[0], z1a);
      z1b = MF(a1, wp1[1], z1b);
      f32x4 zf = z1a + z1b;
#pragma unroll
      for (int r = 0; r < 4; ++r) zb[w][q * 4 + r][m] = zf[r];
    }
    __syncthreads();

    // ---- P5: L1 gates + h1_t tagged store (no drain, no signal) ----
    {
      float iv = zb[0][row2][col2] + b0i;
      float fv = zb[1][row2][col2] + b0f;
      float gv = zb[2][row2][col2] + b0g;
      float ov = zb[3][row2][col2] + b0o;
      float ig = sigf(iv), fg = sigf(fv), gg = tanhfast(gv), og = sigf(ov);
      c1v = fg * c1v + ig * gg;
      float hn = og * tanhfast(c1v);
      unsigned hv = (unsigned)__builtin_bit_cast(unsigned short, __float2bfloat16(hn));
      st_llc_u32(&h1t[gsidx], ((unsigned)t << 16) | hv);
    }

    // ---- P6: z2 h2-half (gate w, 16 chunks) - fills the h1 rendezvous ----
    f32x4 z2a = {0.f,0.f,0.f,0.f}, z2b = {0.f,0.f,0.f,0.f};
#pragma unroll
    for (int c = 0; c < 16; c += 2) {
      v8bf a0 = ldv(&h2L[m][(c * 32 + q * 8) ^ sw]);
      v8bf a1 = ldv(&h2L[m][((c + 1) * 32 + q * 8) ^ sw]);
      z2a = MF(a0, wp2[16 + c], z2a);
      z2b = MF(a1, wp2[17 + c], z2b);
    }

    // ---- P7: tagged poll+land h1_t -> h1N ----
    poll_land(h1slice, (unsigned)t, (char*)&h1N[row2][0], so0, ssw);
    __syncthreads();

    // ---- P8: z2 h1-half + z2 gate tile -> zb ----
    {
#pragma unroll
      for (int c = 0; c < 16; c += 2) {
        v8bf a0 = ldv(&h1N[m][(c * 32 + q * 8) ^ sw]);
        v8bf a1 = ldv(&h1N[m][((c + 1) * 32 + q * 8) ^ sw]);
        z2a = MF(a0, wp2[c], z2a);
        z2b = MF(a1, wp2[c + 1], z2b);
      }
      f32x4 zf = z2a + z2b;
#pragma unroll
      for (int r = 0; r < 4; ++r) zb[w][q * 4 + r][m] = zf[r];
    }
    __syncthreads();

    // ---- P9: L2 gates + h2_t tagged store (or last_cell at t==T-1) ----
    {
      float iv = zb[0][row2][col2] + b1i;
      float fv = zb[1][row2][col2] + b1f;
      float gv = zb[2][row2][col2] + b1g;
      float ov = zb[3][row2][col2] + b1o;
      float ig = sigf(iv), fg = sigf(fv), gg = tanhfast(gv), og = sigf(ov);
      c2v = fg * c2v + ig * gg;
      float hn = og * tanhfast(c2v);
      if (t == T_ - 1) {
        last_out[hidx] = hn;
      } else {
        unsigned hv = (unsigned)__builtin_bit_cast(unsigned short, __float2bfloat16(hn));
        st_llc_u32(&h2t[gsidx], ((unsigned)t << 16) | hv);
      }
    }
  }
}

// ---------------------------------------------------------------------------
extern "C" void kernel_launch(void* const* d_in, const int* in_sizes, int n_in,
                              void* d_out, int out_size, void* d_ws, size_t ws_size,
                              hipStream_t stream) {
  const float* x    = (const float*)d_in[0];
  const float* k0   = (const float*)d_in[1];
  const float* r0   = (const float*)d_in[2];
  const float* b0   = (const float*)d_in[3];
  const float* k1   = (const float*)d_in[4];
  const float* r1   = (const float*)d_in[5];
  const float* b1   = (const float*)d_in[6];
  const float* W    = (const float*)d_in[7];
  const float* bias = (const float*)d_in[8];

  char* ws = (char*)d_ws;
  __hip_bfloat16* Wp1 = (__hip_bfloat16*)(ws + OFF_WP1);
  __hip_bfloat16* Wp2 = (__hip_bfloat16*)(ws + OFF_WP2);
  __hip_bfloat16* WpP = (__hip_bfloat16*)(ws + OFF_WPP);
  unsigned*       h1t = (unsigned*)(ws + OFF_H1T);
  unsigned*       h2t = (unsigned*)(ws + OFF_H2T);

  pack_weights<<<(128 * 18 * 64 + 255) / 256, 256, 0, stream>>>(k0, r0, 64, 2048, 18, 128, Wp1);
  pack_weights<<<(128 * 32 * 64 + 255) / 256, 256, 0, stream>>>(k1, r1, 512, 2048, 32, 128, Wp2);
  pack_weights<<<(4 * 16 * 64 + 255) / 256, 256, 0, stream>>>(W, W, 512, 64, 16, 4, WpP);
  init_state<<<256, 256, 0, stream>>>(h1t, h2t);

  float* outp = (float*)d_out;
  float* last = outp + (size_t)B_ * (T_ - 1) * D_;

  rnn_persist<<<256, 256, 0, stream>>>(x, Wp1, Wp2, WpP, b0, b1, bias,
                                       h1t, h2t, outp, last);
}

// Round 6
// 1752.115 us; speedup vs baseline: 1.2193x; 1.2193x over previous
//
#include <hip/hip_runtime.h>
#include <hip/hip_bf16.h>

// ---------------------------------------------------------------------------
// AJ-RNN forward: 2-layer LSTM (B=128,T=256,D=64,H=512) with missing-value
// imputation. Round 9: R6 gate-split structure (best, 1515us) +
//  (1) flag-array barrier: per-block ticket store (no RMW) + wave-0 poll of
//      one 128B flag line  [R6 used 32-block fetch_add on ONE word: ~2-3k cyc
//      of LLC RMW serialization per barrier]
//  (2) load-RTT cover: z1-h1 and z2-h2 split 8+8 MFMAs around the h-load
//      issue, so the LLC data-load RTT is hidden under compute
//  (3) pred->cur merged in MFMA lane layout (no predb LDS round-trip)
//  - h exchange at the LLC coherence point (sc0 sc1), zero cache maintenance
//  - weights register-resident; c1/c2 in registers; h1 LDS ping-pong
// ---------------------------------------------------------------------------

typedef __bf16        v8bf  __attribute__((ext_vector_type(8)));
typedef float         f32x4 __attribute__((ext_vector_type(4)));
typedef unsigned int  u32x4 __attribute__((ext_vector_type(4)));

constexpr int B_ = 128, T_ = 256, D_ = 64, H_ = 512;

// workspace layout (bytes)
constexpr size_t OFF_WP1 = 0;        // packed [k0;r0] bf16 -> 2359296 B
constexpr size_t OFF_WP2 = 2359296;  // packed [k1;r1] bf16 -> 4194304 B
constexpr size_t OFF_WPP = 6553600;  // packed W bf16       ->   65536 B
constexpr size_t OFF_H1G = 6619136;  // h1 exchange bf16       131072 B
constexpr size_t OFF_H2G = 6750208;  // h2 exchange bf16       131072 B
constexpr size_t OFF_FLG = 6881280;  // 8 chains * 64 u32 =      2048 B

__device__ __forceinline__ v8bf ldv(const __hip_bfloat16* p) {
  return *reinterpret_cast<const v8bf*>(p);
}
__device__ __forceinline__ f32x4 MF(v8bf a, v8bf b, f32x4 c) {
  return __builtin_amdgcn_mfma_f32_16x16x32_bf16(a, b, c, 0, 0, 0);
}
__device__ __forceinline__ float sigf(float x) { return 1.0f / (1.0f + __expf(-x)); }
__device__ __forceinline__ float tanhfast(float x) {
  x = fminf(15.0f, fmaxf(-15.0f, x));
  float e = __expf(-2.0f * x);
  return (1.0f - e) / (1.0f + e);
}

// stores straight to the device coherence point (LLC)
__device__ __forceinline__ void st_llc_u16(void* p, unsigned v) {
  asm volatile("global_store_short %0, %1, off sc0 sc1" :: "v"(p), "v"(v) : "memory");
}
__device__ __forceinline__ void st_flag(unsigned* p, unsigned v) {
  asm volatile("global_store_dword %0, %1, off sc0 sc1" :: "v"(p), "v"(v) : "memory");
}
__device__ __forceinline__ void vm0() {
  asm volatile("s_waitcnt vmcnt(0)" ::: "memory");
}
// issue 64B of LLC loads (bypass L1/L2); land later after vm0()
__device__ __forceinline__ void ld_llc64_issue(const char* g, u32x4& a, u32x4& b,
                                               u32x4& c, u32x4& d) {
  asm volatile(
      "global_load_dwordx4 %0, %4, off sc0 sc1\n\t"
      "global_load_dwordx4 %1, %4, off offset:16 sc0 sc1\n\t"
      "global_load_dwordx4 %2, %4, off offset:32 sc0 sc1\n\t"
      "global_load_dwordx4 %3, %4, off offset:48 sc0 sc1"
      : "=&v"(a), "=&v"(b), "=&v"(c), "=&v"(d)
      : "v"(g)
      : "memory");
}
// wave-0 poll of the chain's 32-flag line (one coalesced load per iteration)
__device__ __forceinline__ void poll_flags(const unsigned* fbase, int lane,
                                           unsigned tgt) {
  const unsigned* fp = fbase + (lane & 31);
  for (;;) {
    unsigned f;
    asm volatile("global_load_dword %0, %1, off sc0 sc1\n\ts_waitcnt vmcnt(0)"
                 : "=v"(f) : "v"(fp) : "memory");
    if (!__any((int)(f < tgt))) return;
  }
}

// ---------------------------------------------------------------------------
// Pack B-operand fragments (float32 in, bf16 out):
// out[((ct*nkc + kc)*64 + lane)*8 + j] = Wcat[kc*32 + (lane>>4)*8 + j][ct*16 + (lane&15)]
// ---------------------------------------------------------------------------
__global__ __launch_bounds__(256) void pack_weights(
    const float* __restrict__ kp, const float* __restrict__ rp,
    int krows, int ncols, int nkc, int nct, __hip_bfloat16* __restrict__ out) {
  int tid = blockIdx.x * 256 + threadIdx.x;
  int total = nct * nkc * 64;
  if (tid >= total) return;
  int L  = tid & 63;
  int kc = (tid >> 6) % nkc;
  int ct = tid / (64 * nkc);
  int n  = ct * 16 + (L & 15);
  int kb = kc * 32 + (L >> 4) * 8;
  __hip_bfloat16* dst = out + (size_t)tid * 8;
#pragma unroll
  for (int j = 0; j < 8; ++j) {
    int kk = kb + j;
    float v = (kk < krows) ? kp[kk * ncols + n] : rp[(kk - krows) * ncols + n];
    dst[j] = __float2bfloat16(v);
  }
}

// zero the 512 barrier flags (ws re-poisoned to 0xAA before every call).
// h1g/h2g need no init: every read is flag-gated behind its producer store.
__global__ __launch_bounds__(256) void init_state(unsigned* __restrict__ flg) {
  int idx = blockIdx.x * 256 + threadIdx.x;
  if (idx < 512) flg[idx] = 0u;
}

// ---------------------------------------------------------------------------
// Persistent recurrence kernel. Block = (rg,cg): 16 batch rows x 16 h-cols,
// 4 waves (gate-split: wave w = gate w). 8 chains of 32 blocks; rg=blockIdx&7
// (round-robin XCD grouping heuristic; correctness never depends on it).
// Barrier values: barrier-1(t) = 2t+1 (h1_t ready), barrier-2(t) = 2t+2.
// Overwrite safety of single h buffers: block X stores h1(t+1) only after
// observing barrier-2(t), which requires every block to have stored h2(t),
// which happens after that block consumed h1(t). Same argument for h2.
// ---------------------------------------------------------------------------
__global__ __launch_bounds__(256, 1) void rnn_persist(
    const float* __restrict__ x,
    const __hip_bfloat16* __restrict__ Wp1,
    const __hip_bfloat16* __restrict__ Wp2,
    const __hip_bfloat16* __restrict__ WpP,
    const float* __restrict__ b0,
    const float* __restrict__ b1,
    const float* __restrict__ biasD,
    __hip_bfloat16* __restrict__ h1g,
    __hip_bfloat16* __restrict__ h2g,
    unsigned* __restrict__ flg,
    float* __restrict__ pred_out,
    float* __restrict__ last_out) {

  // h tiles: 1024B rows, XOR-swizzled (phys_byte = log_byte ^ ((row&7)<<4))
  __shared__ alignas(16) __hip_bfloat16 h1P[16][512];
  __shared__ alignas(16) __hip_bfloat16 h1Q[16][512];
  __shared__ alignas(16) __hip_bfloat16 h2L[16][512];
  __shared__ alignas(16) __hip_bfloat16 curL[16][72];
  __shared__ float zb[4][16][17];

  const int tid = threadIdx.x;
  const int rg = blockIdx.x & 7;
  const int cg = blockIdx.x >> 3;
  const int w  = tid >> 6;
  const int L  = tid & 63;
  const int m  = L & 15;
  const int q  = L >> 4;
  const int row2 = tid >> 4;
  const int col2 = tid & 15;
  const int C  = cg * 16 + col2;
  const int R  = rg * 16 + row2;
  const int sw = (m & 7) << 3;          // element-unit LDS read swizzle

  // per-thread 64B stage slot: row (tid>>4), bytes (tid&15)*64..+63
  const int so0 = col2 * 64;
  const int ssw = (row2 & 7) << 4;
  const size_t gso = (size_t)row2 * 1024 + so0;

  // ---- weight fragments into registers, once (gate-split layout) ----
  v8bf wpp[16], wp1[18], wp2[32];
  {
    const int ct = w * 32 + cg;
#pragma unroll
    for (int kc = 0; kc < 16; ++kc)
      wpp[kc] = ldv(WpP + ((size_t)(w * 16 + kc) * 64 + L) * 8);
#pragma unroll
    for (int kc = 0; kc < 18; ++kc)
      wp1[kc] = ldv(Wp1 + ((size_t)(ct * 18 + kc) * 64 + L) * 8);
#pragma unroll
    for (int kc = 0; kc < 32; ++kc)
      wp2[kc] = ldv(Wp2 + ((size_t)(ct * 32 + kc) * 64 + L) * 8);
  }
  const float b0i = b0[C], b0f = b0[512 + C], b0g = b0[1024 + C], b0o = b0[1536 + C];
  const float b1i = b1[C], b1f = b1[512 + C], b1g = b1[1024 + C], b1o = b1[1536 + C];
  const float bD  = biasD[w * 16 + m];

  float c1v = 0.0f, c2v = 0.0f;         // cell state in registers

  const size_t rgbase = (size_t)rg * 16 * H_;
  unsigned* fbase = flg + (rg << 6);
  const int hidx = R * H_ + C;
  // pred/cur lane-layout row base: rows q*4+r, col w*16+m
  const int prow0 = rg * 16 + q * 4;
  const int pcol  = w * 16 + m;

  // prologue: h1(-1)=0 (ping) and h2(-1)=0 directly in LDS
  {
    u32x4 zz = {0u, 0u, 0u, 0u};
    u32x4* p1 = reinterpret_cast<u32x4*>(&h1P[0][0]);
    u32x4* p2 = reinterpret_cast<u32x4*>(&h2L[0][0]);
#pragma unroll
    for (int i = 0; i < 4; ++i) { p1[tid * 4 + i] = zz; p2[tid * 4 + i] = zz; }
  }
  __syncthreads();

  for (int t = 0; t < T_; ++t) {
    __hip_bfloat16 (*h1L)[512] = (t & 1) ? h1Q : h1P;  // h1_{t-1}
    __hip_bfloat16 (*h1N)[512] = (t & 1) ? h1P : h1Q;  // h1_t (landed below)

    // ---- z1 h1-part, first 8 chunks (covers producers' h2-store skew) ----
    f32x4 z1a = {0.f,0.f,0.f,0.f}, z1b = {0.f,0.f,0.f,0.f};
#pragma unroll
    for (int c = 0; c < 8; c += 2) {
      v8bf a0 = ldv(&h1L[m][(c * 32 + q * 8) ^ sw]);
      v8bf a1 = ldv(&h1L[m][((c + 1) * 32 + q * 8) ^ sw]);
      z1a = MF(a0, wp1[2 + c], z1a);
      z1b = MF(a1, wp1[3 + c], z1b);
    }

    // ---- barrier-2(t-1): h2_{t-1} ready at LLC ----
    if (t > 0 && w == 0) poll_flags(fbase, L, 2u * (unsigned)t);
    __syncthreads();

    // ---- issue h2 loads; cover with z1 h1-part chunks 8..15; land ----
    u32x4 sa, sb, sc2, sd;
    if (t > 0)
      ld_llc64_issue((const char*)(h2g + rgbase) + gso, sa, sb, sc2, sd);
#pragma unroll
    for (int c = 8; c < 16; c += 2) {
      v8bf a0 = ldv(&h1L[m][(c * 32 + q * 8) ^ sw]);
      v8bf a1 = ldv(&h1L[m][((c + 1) * 32 + q * 8) ^ sw]);
      z1a = MF(a0, wp1[2 + c], z1a);
      z1b = MF(a1, wp1[3 + c], z1b);
    }
    if (t > 0) {
      vm0();
      char* lb = (char*)(&h2L[row2][0]);
      *(u32x4*)(lb + ((so0 +  0) ^ ssw)) = sa;
      *(u32x4*)(lb + ((so0 + 16) ^ ssw)) = sb;
      *(u32x4*)(lb + ((so0 + 32) ^ ssw)) = sc2;
      *(u32x4*)(lb + ((so0 + 48) ^ ssw)) = sd;
    }
    __syncthreads();

    // ---- pred (MFMA lane layout) -> cur build -> curL, pred d_out ----
    {
      f32x4 a0 = {0.f,0.f,0.f,0.f};
      if (t > 0) {
        f32x4 a1 = {0.f,0.f,0.f,0.f};
#pragma unroll
        for (int kc = 0; kc < 16; kc += 2) {
          v8bf x0 = ldv(&h2L[m][(kc * 32 + q * 8) ^ sw]);
          v8bf x1 = ldv(&h2L[m][((kc + 1) * 32 + q * 8) ^ sw]);
          a0 = MF(x0, wpp[kc], a0);
          a1 = MF(x1, wpp[kc + 1], a1);
        }
        a0 += a1;
      }
#pragma unroll
      for (int r = 0; r < 4; ++r) {
        const int rowl = prow0 + r;                       // global batch row
        const float xf = x[((size_t)rowl * T_ + t) * D_ + pcol];
        float pv = a0[r] + bD;
        const bool missv = (t > 0) && (xf == 128.0f);
        curL[q * 4 + r][pcol] = __float2bfloat16(missv ? pv : xf);
        if (cg == 0 && t > 0)
          pred_out[((size_t)rowl * (T_ - 1) + (t - 1)) * D_ + pcol] = pv;
      }
    }
    __syncthreads();

    // ---- z1 cur-part + gate tile -> zb ----
    {
      v8bf a0 = ldv(&curL[m][q * 8]);
      v8bf a1 = ldv(&curL[m][32 + q * 8]);
      z1a = MF(a0, wp1[0], z1a);
      z1b = MF(a1, wp1[1], z1b);
      f32x4 zf = z1a + z1b;
#pragma unroll
      for (int r = 0; r < 4; ++r) zb[w][q * 4 + r][m] = zf[r];
    }
    __syncthreads();

    // ---- L1 gates + h1_t store to LLC; drain; signal barrier-1 ----
    {
      float iv = zb[0][row2][col2] + b0i;
      float fv = zb[1][row2][col2] + b0f;
      float gv = zb[2][row2][col2] + b0g;
      float ov = zb[3][row2][col2] + b0o;
      float ig = sigf(iv), fg = sigf(fv), gg = tanhfast(gv), og = sigf(ov);
      c1v = fg * c1v + ig * gg;
      float hn = og * tanhfast(c1v);
      st_llc_u16(&h1g[hidx], (unsigned)__builtin_bit_cast(unsigned short,
                                                          __float2bfloat16(hn)));
    }
    vm0();
    __syncthreads();
    if (tid == 0) st_flag(fbase + cg, 2u * (unsigned)t + 1u);

    // ---- z2 h2-half, first 8 chunks (covers barrier-1 skew/poll) ----
    f32x4 z2a = {0.f,0.f,0.f,0.f}, z2b = {0.f,0.f,0.f,0.f};
#pragma unroll
    for (int c = 0; c < 8; c += 2) {
      v8bf a0 = ldv(&h2L[m][(c * 32 + q * 8) ^ sw]);
      v8bf a1 = ldv(&h2L[m][((c + 1) * 32 + q * 8) ^ sw]);
      z2a = MF(a0, wp2[16 + c], z2a);
      z2b = MF(a1, wp2[17 + c], z2b);
    }
    if (w == 0) poll_flags(fbase, L, 2u * (unsigned)t + 1u);
    __syncthreads();

    // ---- issue h1_t loads; cover with z2 h2-half chunks 8..15; land ----
    ld_llc64_issue((const char*)(h1g + rgbase) + gso, sa, sb, sc2, sd);
#pragma unroll
    for (int c = 8; c < 16; c += 2) {
      v8bf a0 = ldv(&h2L[m][(c * 32 + q * 8) ^ sw]);
      v8bf a1 = ldv(&h2L[m][((c + 1) * 32 + q * 8) ^ sw]);
      z2a = MF(a0, wp2[16 + c], z2a);
      z2b = MF(a1, wp2[17 + c], z2b);
    }
    vm0();
    {
      char* lb = (char*)(&h1N[row2][0]);
      *(u32x4*)(lb + ((so0 +  0) ^ ssw)) = sa;
      *(u32x4*)(lb + ((so0 + 16) ^ ssw)) = sb;
      *(u32x4*)(lb + ((so0 + 32) ^ ssw)) = sc2;
      *(u32x4*)(lb + ((so0 + 48) ^ ssw)) = sd;
    }
    __syncthreads();

    // ---- z2 h1-half + gate tile -> zb ----
    {
#pragma unroll
      for (int c = 0; c < 16; c += 2) {
        v8bf a0 = ldv(&h1N[m][(c * 32 + q * 8) ^ sw]);
        v8bf a1 = ldv(&h1N[m][((c + 1) * 32 + q * 8) ^ sw]);
        z2a = MF(a0, wp2[c], z2a);
        z2b = MF(a1, wp2[c + 1], z2b);
      }
      f32x4 zf = z2a + z2b;
#pragma unroll
      for (int r = 0; r < 4; ++r) zb[w][q * 4 + r][m] = zf[r];
    }
    __syncthreads();

    // ---- L2 gates + h2_t store (or last_cell); signal barrier-2 ----
    {
      float iv = zb[0][row2][col2] + b1i;
      float fv = zb[1][row2][col2] + b1f;
      float gv = zb[2][row2][col2] + b1g;
      float ov = zb[3][row2][col2] + b1o;
      float ig = sigf(iv), fg = sigf(fv), gg = tanhfast(gv), og = sigf(ov);
      c2v = fg * c2v + ig * gg;
      float hn = og * tanhfast(c2v);
      if (t == T_ - 1) {
        last_out[hidx] = hn;
      } else {
        st_llc_u16(&h2g[hidx], (unsigned)__builtin_bit_cast(unsigned short,
                                                            __float2bfloat16(hn)));
      }
    }
    if (t == T_ - 1) break;
    vm0();
    __syncthreads();
    if (tid == 0) st_flag(fbase + cg, 2u * (unsigned)t + 2u);
  }
}

// ---------------------------------------------------------------------------
extern "C" void kernel_launch(void* const* d_in, const int* in_sizes, int n_in,
                              void* d_out, int out_size, void* d_ws, size_t ws_size,
                              hipStream_t stream) {
  const float* x    = (const float*)d_in[0];
  const float* k0   = (const float*)d_in[1];
  const float* r0   = (const float*)d_in[2];
  const float* b0   = (const float*)d_in[3];
  const float* k1   = (const float*)d_in[4];
  const float* r1   = (const float*)d_in[5];
  const float* b1   = (const float*)d_in[6];
  const float* W    = (const float*)d_in[7];
  const float* bias = (const float*)d_in[8];

  char* ws = (char*)d_ws;
  __hip_bfloat16* Wp1 = (__hip_bfloat16*)(ws + OFF_WP1);
  __hip_bfloat16* Wp2 = (__hip_bfloat16*)(ws + OFF_WP2);
  __hip_bfloat16* WpP = (__hip_bfloat16*)(ws + OFF_WPP);
  __hip_bfloat16* h1g = (__hip_bfloat16*)(ws + OFF_H1G);
  __hip_bfloat16* h2g = (__hip_bfloat16*)(ws + OFF_H2G);
  unsigned*       flg = (unsigned*)(ws + OFF_FLG);

  pack_weights<<<(128 * 18 * 64 + 255) / 256, 256, 0, stream>>>(k0, r0, 64, 2048, 18, 128, Wp1);
  pack_weights<<<(128 * 32 * 64 + 255) / 256, 256, 0, stream>>>(k1, r1, 512, 2048, 32, 128, Wp2);
  pack_weights<<<(4 * 16 * 64 + 255) / 256, 256, 0, stream>>>(W, W, 512, 64, 16, 4, WpP);
  init_state<<<2, 256, 0, stream>>>(flg);

  float* outp = (float*)d_out;
  float* last = outp + (size_t)B_ * (T_ - 1) * D_;

  rnn_persist<<<256, 256, 0, stream>>>(x, Wp1, Wp2, WpP, b0, b1, bias,
                                       h1g, h2g, flg, outp, last);
}

// Round 7
// 1467.273 us; speedup vs baseline: 1.4560x; 1.1941x over previous
//
#include <hip/hip_runtime.h>
#include <hip/hip_bf16.h>

// ---------------------------------------------------------------------------
// AJ-RNN forward: 2-layer LSTM (B=128,T=256,D=64,H=512) with missing-value
// imputation. Round 10: R6 structure (best, 1515us) + pipelined rendezvous.
//  SINGLE-VARIABLE change vs R6: instruction scheduling only.
//   - drain hide: h-store -> 8 cover MFMAs -> vmcnt(0) -> signal
//   - load hide:  issue h-loads -> 4 cover MFMAs -> vmcnt(0) -> land
//   - z1's h1-half rotated across the loop boundary (accumulators carried);
//     at t=0 the rotated-out chunks are over zeroed h1 == exact 0 contribution
//  Kept from R6 verbatim: fetch_add + s_sleep(1) wave-0 poll barrier, float4
//  x loads, predb LDS round-trip, LLC (sc0 sc1) h exchange, gate-split waves,
//  register weights, register cell state, h1 LDS ping-pong.
// ---------------------------------------------------------------------------

typedef __bf16        v8bf  __attribute__((ext_vector_type(8)));
typedef float         f32x4 __attribute__((ext_vector_type(4)));
typedef unsigned int  u32x4 __attribute__((ext_vector_type(4)));

constexpr int B_ = 128, T_ = 256, D_ = 64, H_ = 512;

// workspace layout (bytes)
constexpr size_t OFF_WP1 = 0;        // packed [k0;r0] bf16 -> 2359296 B
constexpr size_t OFF_WP2 = 2359296;  // packed [k1;r1] bf16 -> 4194304 B
constexpr size_t OFF_WPP = 6553600;  // packed W bf16       ->   65536 B
constexpr size_t OFF_H1G = 6619136;  // h1 exchange bf16       131072 B
constexpr size_t OFF_H2G = 6750208;  // h2 exchange bf16       131072 B
constexpr size_t OFF_FLG = 6881280;  // 8 chains * 64 u32 =      2048 B

__device__ __forceinline__ v8bf ldv(const __hip_bfloat16* p) {
  return *reinterpret_cast<const v8bf*>(p);
}
__device__ __forceinline__ f32x4 MF(v8bf a, v8bf b, f32x4 c) {
  return __builtin_amdgcn_mfma_f32_16x16x32_bf16(a, b, c, 0, 0, 0);
}
__device__ __forceinline__ float sigf(float x) { return 1.0f / (1.0f + __expf(-x)); }
__device__ __forceinline__ float tanhfast(float x) {
  x = fminf(15.0f, fmaxf(-15.0f, x));
  float e = __expf(-2.0f * x);
  return (1.0f - e) / (1.0f + e);
}

// store straight to the device coherence point (LLC)
__device__ __forceinline__ void st_llc_u16(void* p, unsigned v) {
  asm volatile("global_store_short %0, %1, off sc0 sc1" :: "v"(p), "v"(v) : "memory");
}
__device__ __forceinline__ void vm0() {
  asm volatile("s_waitcnt vmcnt(0)" ::: "memory");
}
// issue 64B of LLC loads (bypass L1/L2); land later after vm0()
__device__ __forceinline__ void ld_llc64_issue(const char* g, u32x4& a, u32x4& b,
                                               u32x4& c, u32x4& d) {
  asm volatile(
      "global_load_dwordx4 %0, %4, off sc0 sc1\n\t"
      "global_load_dwordx4 %1, %4, off offset:16 sc0 sc1\n\t"
      "global_load_dwordx4 %2, %4, off offset:32 sc0 sc1\n\t"
      "global_load_dwordx4 %3, %4, off offset:48 sc0 sc1"
      : "=&v"(a), "=&v"(b), "=&v"(c), "=&v"(d)
      : "v"(g)
      : "memory");
}

// ---------------------------------------------------------------------------
// Pack B-operand fragments (float32 in, bf16 out):
// out[((ct*nkc + kc)*64 + lane)*8 + j] = Wcat[kc*32 + (lane>>4)*8 + j][ct*16 + (lane&15)]
// ---------------------------------------------------------------------------
__global__ __launch_bounds__(256) void pack_weights(
    const float* __restrict__ kp, const float* __restrict__ rp,
    int krows, int ncols, int nkc, int nct, __hip_bfloat16* __restrict__ out) {
  int tid = blockIdx.x * 256 + threadIdx.x;
  int total = nct * nkc * 64;
  if (tid >= total) return;
  int L  = tid & 63;
  int kc = (tid >> 6) % nkc;
  int ct = tid / (64 * nkc);
  int n  = ct * 16 + (L & 15);
  int kb = kc * 32 + (L >> 4) * 8;
  __hip_bfloat16* dst = out + (size_t)tid * 8;
#pragma unroll
  for (int j = 0; j < 8; ++j) {
    int kk = kb + j;
    float v = (kk < krows) ? kp[kk * ncols + n] : rp[(kk - krows) * ncols + n];
    dst[j] = __float2bfloat16(v);
  }
}

// zero the barrier counters (ws re-poisoned to 0xAA before every call).
// h1g/h2g need no init: every read is barrier-gated behind its producer store.
__global__ __launch_bounds__(256) void init_state(unsigned* __restrict__ flg) {
  int idx = blockIdx.x * 256 + threadIdx.x;
  if (idx < 512) flg[idx] = 0u;
}

// ---------------------------------------------------------------------------
// Persistent recurrence kernel. Block = (rg,cg): 16 batch rows x 16 h-cols,
// 4 waves (gate-split: wave w = gate w). 8 chains of 32 blocks; rg=blockIdx&7.
// Monotonic counter barrier: after barrier-1(t) counter==32*(2t+1); after
// barrier-2(t) counter==32*(2t+2). Single h buffers are overwrite-safe: a
// block stores h1(t+1) only after observing barrier-2(t), which requires all
// blocks to have stored h2(t), which happens after each consumed h1(t).
// ---------------------------------------------------------------------------
__global__ __launch_bounds__(256, 1) void rnn_persist(
    const float* __restrict__ x,
    const __hip_bfloat16* __restrict__ Wp1,
    const __hip_bfloat16* __restrict__ Wp2,
    const __hip_bfloat16* __restrict__ WpP,
    const float* __restrict__ b0,
    const float* __restrict__ b1,
    const float* __restrict__ biasD,
    __hip_bfloat16* __restrict__ h1g,
    __hip_bfloat16* __restrict__ h2g,
    unsigned* __restrict__ flg,
    float* __restrict__ pred_out,
    float* __restrict__ last_out) {

  // h tiles: 1024B rows, XOR-swizzled (phys_byte = log_byte ^ ((row&7)<<4))
  __shared__ alignas(16) __hip_bfloat16 h1P[16][512];
  __shared__ alignas(16) __hip_bfloat16 h1Q[16][512];
  __shared__ alignas(16) __hip_bfloat16 h2L[16][512];
  __shared__ alignas(16) __hip_bfloat16 curL[16][72];
  __shared__ alignas(16) float predb[16][68];
  __shared__ float zb[4][16][17];

  const int tid = threadIdx.x;
  const int rg = blockIdx.x & 7;
  const int cg = blockIdx.x >> 3;
  const int w  = tid >> 6;
  const int L  = tid & 63;
  const int m  = L & 15;
  const int q  = L >> 4;
  const int row2 = tid >> 4;
  const int col2 = tid & 15;
  const int C  = cg * 16 + col2;
  const int R  = rg * 16 + row2;
  const int c0 = col2 * 4;
  const int sw = (m & 7) << 3;          // element-unit LDS read swizzle

  // per-thread 64B stage slot: row (tid>>4), bytes (tid&15)*64..+63
  const int so0 = col2 * 64;
  const int ssw = (row2 & 7) << 4;
  const size_t gso = (size_t)row2 * 1024 + so0;

  // ---- weight fragments into registers, once (gate-split layout) ----
  v8bf wpp[16], wp1[18], wp2[32];
  {
    const int ct = w * 32 + cg;
#pragma unroll
    for (int kc = 0; kc < 16; ++kc)
      wpp[kc] = ldv(WpP + ((size_t)(w * 16 + kc) * 64 + L) * 8);
#pragma unroll
    for (int kc = 0; kc < 18; ++kc)
      wp1[kc] = ldv(Wp1 + ((size_t)(ct * 18 + kc) * 64 + L) * 8);
#pragma unroll
    for (int kc = 0; kc < 32; ++kc)
      wp2[kc] = ldv(Wp2 + ((size_t)(ct * 32 + kc) * 64 + L) * 8);
  }
  const float b0i = b0[C], b0f = b0[512 + C], b0g = b0[1024 + C], b0o = b0[1536 + C];
  const float b1i = b1[C], b1f = b1[512 + C], b1g = b1[1024 + C], b1o = b1[1536 + C];
  const float bD  = biasD[w * 16 + m];

  float c1v = 0.0f, c2v = 0.0f;         // cell state in registers

  const size_t rgbase = (size_t)rg * 16 * H_;
  const float* xrow = x + (size_t)R * T_ * D_;
  float* prow = pred_out + (size_t)R * (T_ - 1) * D_;
  unsigned* cnt = flg + rg * 64;
  const int hidx = R * H_ + C;

  // prologue: h1(-1)=0 (ping) and h2(-1)=0 directly in LDS
  {
    u32x4 zz = {0u, 0u, 0u, 0u};
    u32x4* p1 = reinterpret_cast<u32x4*>(&h1P[0][0]);
    u32x4* p2 = reinterpret_cast<u32x4*>(&h2L[0][0]);
#pragma unroll
    for (int i = 0; i < 4; ++i) { p1[tid * 4 + i] = zz; p2[tid * 4 + i] = zz; }
  }
  __syncthreads();

  // z1 h1-half accumulators, carried across the loop boundary (pipelined).
  // For t=0 the rotated-out chunks [0..8) were over h1(-1)=0 -> contribute 0.
  f32x4 z1a = {0.f,0.f,0.f,0.f}, z1b = {0.f,0.f,0.f,0.f};

  for (int t = 0; t < T_; ++t) {
    __hip_bfloat16 (*h1L)[512] = (t & 1) ? h1Q : h1P;  // h1_{t-1}
    __hip_bfloat16 (*h1N)[512] = (t & 1) ? h1P : h1Q;  // h1_t (landed below)

    const float4 xv = *reinterpret_cast<const float4*>(xrow + t * D_ + c0);

    // ---- P1: z1 h1 chunks [8..12); wave-0 polls barrier-2(t-1) ----
#pragma unroll
    for (int c = 8; c < 12; c += 2) {
      v8bf a0 = ldv(&h1L[m][(c * 32 + q * 8) ^ sw]);
      v8bf a1 = ldv(&h1L[m][((c + 1) * 32 + q * 8) ^ sw]);
      z1a = MF(a0, wp1[2 + c], z1a);
      z1b = MF(a1, wp1[3 + c], z1b);
    }
    if (t > 0 && tid < 64) {
      const unsigned tgt = 64u * (unsigned)t;          // 32*(2(t-1)+2)
      while (__hip_atomic_load(cnt, __ATOMIC_RELAXED, __HIP_MEMORY_SCOPE_AGENT) < tgt)
        __builtin_amdgcn_s_sleep(1);
    }
    __syncthreads();

    // ---- P2: issue h2 loads; cover with z1 h1 chunks [12..16); land ----
    u32x4 sa, sb, sc2, sd;
    if (t > 0)
      ld_llc64_issue((const char*)(h2g + rgbase) + gso, sa, sb, sc2, sd);
#pragma unroll
    for (int c = 12; c < 16; c += 2) {
      v8bf a0 = ldv(&h1L[m][(c * 32 + q * 8) ^ sw]);
      v8bf a1 = ldv(&h1L[m][((c + 1) * 32 + q * 8) ^ sw]);
      z1a = MF(a0, wp1[2 + c], z1a);
      z1b = MF(a1, wp1[3 + c], z1b);
    }
    if (t > 0) {
      vm0();
      char* lb = (char*)(&h2L[row2][0]);
      *(u32x4*)(lb + ((so0 +  0) ^ ssw)) = sa;
      *(u32x4*)(lb + ((so0 + 16) ^ ssw)) = sb;
      *(u32x4*)(lb + ((so0 + 32) ^ ssw)) = sc2;
      *(u32x4*)(lb + ((so0 + 48) ^ ssw)) = sd;
    }
    __syncthreads();

    // ---- P3: pred = h2_{t-1} @ W + bias (wave w: cols w*16..+15) ----
    if (t > 0) {
      f32x4 a0 = {0.f,0.f,0.f,0.f}, a1 = {0.f,0.f,0.f,0.f};
#pragma unroll
      for (int kc = 0; kc < 16; kc += 2) {
        v8bf x0 = ldv(&h2L[m][(kc * 32 + q * 8) ^ sw]);
        v8bf x1 = ldv(&h2L[m][((kc + 1) * 32 + q * 8) ^ sw]);
        a0 = MF(x0, wpp[kc], a0);
        a1 = MF(x1, wpp[kc + 1], a1);
      }
      a0 += a1;
#pragma unroll
      for (int r = 0; r < 4; ++r) predb[q * 4 + r][w * 16 + m] = a0[r] + bD;
    }
    __syncthreads();

    // ---- P4: cur build; cg==0 streams pred -> d_out ----
    {
      float4 pv = {0.f, 0.f, 0.f, 0.f};
      if (t > 0) pv = *reinterpret_cast<const float4*>(&predb[row2][c0]);
      const float xa[4] = {xv.x, xv.y, xv.z, xv.w};
      const float pa[4] = {pv.x, pv.y, pv.z, pv.w};
#pragma unroll
      for (int j = 0; j < 4; ++j) {
        const bool missv = (t > 0) && (xa[j] == 128.0f);
        curL[row2][c0 + j] = __float2bfloat16(missv ? pa[j] : xa[j]);
      }
      if (cg == 0 && t > 0)
        *reinterpret_cast<float4*>(prow + (size_t)(t - 1) * D_ + c0) = pv;
    }
    __syncthreads();

    // ---- P5: z1 cur-part + gate tile -> zb ----
    {
      v8bf a0 = ldv(&curL[m][q * 8]);
      v8bf a1 = ldv(&curL[m][32 + q * 8]);
      z1a = MF(a0, wp1[0], z1a);
      z1b = MF(a1, wp1[1], z1b);
      f32x4 zf = z1a + z1b;
#pragma unroll
      for (int r = 0; r < 4; ++r) zb[w][q * 4 + r][m] = zf[r];
    }
    __syncthreads();

    // ---- P6: L1 gates; h1_t store; 8 z2-h2 cover MFMAs; drain; signal ----
    f32x4 z2a = {0.f,0.f,0.f,0.f}, z2b = {0.f,0.f,0.f,0.f};
    {
      float iv = zb[0][row2][col2] + b0i;
      float fv = zb[1][row2][col2] + b0f;
      float gv = zb[2][row2][col2] + b0g;
      float ov = zb[3][row2][col2] + b0o;
      float ig = sigf(iv), fg = sigf(fv), gg = tanhfast(gv), og = sigf(ov);
      c1v = fg * c1v + ig * gg;
      float hn = og * tanhfast(c1v);
      st_llc_u16(&h1g[hidx], (unsigned)__builtin_bit_cast(unsigned short,
                                                          __float2bfloat16(hn)));
    }
#pragma unroll
    for (int c = 0; c < 8; c += 2) {           // drain cover
      v8bf a0 = ldv(&h2L[m][(c * 32 + q * 8) ^ sw]);
      v8bf a1 = ldv(&h2L[m][((c + 1) * 32 + q * 8) ^ sw]);
      z2a = MF(a0, wp2[16 + c], z2a);
      z2b = MF(a1, wp2[17 + c], z2b);
    }
    vm0();
    __syncthreads();
    if (tid == 0)
      __hip_atomic_fetch_add(cnt, 1u, __ATOMIC_RELAXED, __HIP_MEMORY_SCOPE_AGENT);

    // ---- P7: z2 h2 chunks [8..12); wave-0 polls barrier-1(t) ----
#pragma unroll
    for (int c = 8; c < 12; c += 2) {
      v8bf a0 = ldv(&h2L[m][(c * 32 + q * 8) ^ sw]);
      v8bf a1 = ldv(&h2L[m][((c + 1) * 32 + q * 8) ^ sw]);
      z2a = MF(a0, wp2[16 + c], z2a);
      z2b = MF(a1, wp2[17 + c], z2b);
    }
    if (tid < 64) {
      const unsigned tgt = 32u * (2u * (unsigned)t + 1u);
      while (__hip_atomic_load(cnt, __ATOMIC_RELAXED, __HIP_MEMORY_SCOPE_AGENT) < tgt)
        __builtin_amdgcn_s_sleep(1);
    }
    __syncthreads();

    // ---- P8: issue h1_t loads; cover with z2 h2 chunks [12..16); land ----
    ld_llc64_issue((const char*)(h1g + rgbase) + gso, sa, sb, sc2, sd);
#pragma unroll
    for (int c = 12; c < 16; c += 2) {
      v8bf a0 = ldv(&h2L[m][(c * 32 + q * 8) ^ sw]);
      v8bf a1 = ldv(&h2L[m][((c + 1) * 32 + q * 8) ^ sw]);
      z2a = MF(a0, wp2[16 + c], z2a);
      z2b = MF(a1, wp2[17 + c], z2b);
    }
    vm0();
    {
      char* lb = (char*)(&h1N[row2][0]);
      *(u32x4*)(lb + ((so0 +  0) ^ ssw)) = sa;
      *(u32x4*)(lb + ((so0 + 16) ^ ssw)) = sb;
      *(u32x4*)(lb + ((so0 + 32) ^ ssw)) = sc2;
      *(u32x4*)(lb + ((so0 + 48) ^ ssw)) = sd;
    }
    __syncthreads();

    // ---- P9: z2 h1-half + gate tile -> zb ----
    {
#pragma unroll
      for (int c = 0; c < 16; c += 2) {
        v8bf a0 = ldv(&h1N[m][(c * 32 + q * 8) ^ sw]);
        v8bf a1 = ldv(&h1N[m][((c + 1) * 32 + q * 8) ^ sw]);
        z2a = MF(a0, wp2[c], z2a);
        z2b = MF(a1, wp2[c + 1], z2b);
      }
      f32x4 zf = z2a + z2b;
#pragma unroll
      for (int r = 0; r < 4; ++r) zb[w][q * 4 + r][m] = zf[r];
    }
    __syncthreads();

    // ---- P10: L2 gates; h2_t store (or last_cell); next-step z1 cover;
    //           drain; signal barrier-2 ----
    {
      float iv = zb[0][row2][col2] + b1i;
      float fv = zb[1][row2][col2] + b1f;
      float gv = zb[2][row2][col2] + b1g;
      float ov = zb[3][row2][col2] + b1o;
      float ig = sigf(iv), fg = sigf(fv), gg = tanhfast(gv), og = sigf(ov);
      c2v = fg * c2v + ig * gg;
      float hn = og * tanhfast(c2v);
      if (t == T_ - 1) {
        last_out[hidx] = hn;
        break;
      }
      st_llc_u16(&h2g[hidx], (unsigned)__builtin_bit_cast(unsigned short,
                                                          __float2bfloat16(hn)));
    }
    // next step's z1 h1 chunks [0..8) over h1N (= h1_t), hiding the drain
    z1a = (f32x4){0.f,0.f,0.f,0.f};
    z1b = (f32x4){0.f,0.f,0.f,0.f};
#pragma unroll
    for (int c = 0; c < 8; c += 2) {
      v8bf a0 = ldv(&h1N[m][(c * 32 + q * 8) ^ sw]);
      v8bf a1 = ldv(&h1N[m][((c + 1) * 32 + q * 8) ^ sw]);
      z1a = MF(a0, wp1[2 + c], z1a);
      z1b = MF(a1, wp1[3 + c], z1b);
    }
    vm0();
    __syncthreads();
    if (tid == 0)
      __hip_atomic_fetch_add(cnt, 1u, __ATOMIC_RELAXED, __HIP_MEMORY_SCOPE_AGENT);
  }
}

// ---------------------------------------------------------------------------
extern "C" void kernel_launch(void* const* d_in, const int* in_sizes, int n_in,
                              void* d_out, int out_size, void* d_ws, size_t ws_size,
                              hipStream_t stream) {
  const float* x    = (const float*)d_in[0];
  const float* k0   = (const float*)d_in[1];
  const float* r0   = (const float*)d_in[2];
  const float* b0   = (const float*)d_in[3];
  const float* k1   = (const float*)d_in[4];
  const float* r1   = (const float*)d_in[5];
  const float* b1   = (const float*)d_in[6];
  const float* W    = (const float*)d_in[7];
  const float* bias = (const float*)d_in[8];

  char* ws = (char*)d_ws;
  __hip_bfloat16* Wp1 = (__hip_bfloat16*)(ws + OFF_WP1);
  __hip_bfloat16* Wp2 = (__hip_bfloat16*)(ws + OFF_WP2);
  __hip_bfloat16* WpP = (__hip_bfloat16*)(ws + OFF_WPP);
  __hip_bfloat16* h1g = (__hip_bfloat16*)(ws + OFF_H1G);
  __hip_bfloat16* h2g = (__hip_bfloat16*)(ws + OFF_H2G);
  unsigned*       flg = (unsigned*)(ws + OFF_FLG);

  pack_weights<<<(128 * 18 * 64 + 255) / 256, 256, 0, stream>>>(k0, r0, 64, 2048, 18, 128, Wp1);
  pack_weights<<<(128 * 32 * 64 + 255) / 256, 256, 0, stream>>>(k1, r1, 512, 2048, 32, 128, Wp2);
  pack_weights<<<(4 * 16 * 64 + 255) / 256, 256, 0, stream>>>(W, W, 512, 64, 16, 4, WpP);
  init_state<<<2, 256, 0, stream>>>(flg);

  float* outp = (float*)d_out;
  float* last = outp + (size_t)B_ * (T_ - 1) * D_;

  rnn_persist<<<256, 256, 0, stream>>>(x, Wp1, Wp2, WpP, b0, b1, bias,
                                       h1g, h2g, flg, outp, last);
}